// Round 1
// baseline (654.810 us; speedup 1.0000x reference)
//
#include <hip/hip_runtime.h>

typedef unsigned short u16;
typedef unsigned int   u32;
typedef float  f32x4  __attribute__((ext_vector_type(4)));
typedef float  fltx4  __attribute__((ext_vector_type(4)));
typedef short  bf16x8 __attribute__((ext_vector_type(8)));  // 8 bf16 bits in 4 VGPRs
typedef u32    u32x4  __attribute__((ext_vector_type(4)));

#define CDIM 256
#define NPIX 4096
// (1/sqrt(256)) * log2(e): fold attention scale + exp2 conversion into Q
#define QSCALE 0.09016843736f

__device__ __forceinline__ u16 f2bf(float f) {
  u32 u = __builtin_bit_cast(u32, f);
  u += 0x7fffu + ((u >> 16) & 1u);          // RNE truncate to bf16
  return (u16)(u >> 16);
}

union U8 { bf16x8 v; u16 u[8]; };

// ---------------------------------------------------------------- groupnorm stats
__global__ __launch_bounds__(256) void gn_stats(const float* __restrict__ x,
                                                float* __restrict__ stats) {
  int bg = blockIdx.x;                       // b*32 + g ; group = 8 ch x 4096 contiguous
  const float* base = x + (long)bg * 32768;
  float s = 0.f, s2 = 0.f;
  for (int i = threadIdx.x; i < 8192; i += 256) {
    fltx4 v = ((const fltx4*)base)[i];
    s  += v[0] + v[1] + v[2] + v[3];
    s2 += v[0]*v[0] + v[1]*v[1] + v[2]*v[2] + v[3]*v[3];
  }
  for (int off = 1; off < 64; off <<= 1) {
    s  += __shfl_xor(s, off);
    s2 += __shfl_xor(s2, off);
  }
  __shared__ float red[8];
  int w = threadIdx.x >> 6;
  if ((threadIdx.x & 63) == 0) { red[w] = s; red[4 + w] = s2; }
  __syncthreads();
  if (threadIdx.x == 0) {
    float S  = red[0] + red[1] + red[2] + red[3];
    float S2 = red[4] + red[5] + red[6] + red[7];
    float mean = S * (1.f / 32768.f);
    float var  = S2 * (1.f / 32768.f) - mean * mean;
    stats[bg * 2]     = mean;
    stats[bg * 2 + 1] = rsqrtf(var + 1e-5f);
  }
}

// ------------------------------------------- normalize + transpose -> normT[b][n][c] bf16
__global__ __launch_bounds__(256) void gn_apply(const float* __restrict__ x,
                                                const float* __restrict__ stats,
                                                const float* __restrict__ gamma,
                                                const float* __restrict__ beta,
                                                u16* __restrict__ normT) {
  __shared__ u16 tile[64 * 66];
  const int b = blockIdx.z, cb = blockIdx.y * 64, nb = blockIdx.x * 64;
  const int nIn = threadIdx.x & 63, c4 = threadIdx.x >> 6;
  const float* xb = x + (long)b * (CDIM * NPIX);
  #pragma unroll 4
  for (int p = 0; p < 16; ++p) {
    int cl = c4 * 16 + p;
    int c = cb + cl;
    int g = c >> 3;
    float mean = stats[(b * 32 + g) * 2];
    float rstd = stats[(b * 32 + g) * 2 + 1];
    float v = xb[(long)c * NPIX + nb + nIn];
    tile[cl * 66 + nIn] = f2bf((v - mean) * rstd * gamma[c] + beta[c]);
  }
  __syncthreads();
  u16* nT = normT + ((long)b * NPIX + nb) * CDIM + cb;
  const int cOut = threadIdx.x & 63, n4 = threadIdx.x >> 6;
  #pragma unroll 4
  for (int p = 0; p < 16; ++p) {
    int nl = n4 * 16 + p;
    nT[(long)nl * CDIM + cOut] = tile[cOut * 66 + nl];
  }
}

// ------------------------------------------------------------ generic NT GEMM, K=256
// D[m][n] = sum_k A[m][k]*B[n][k]; A:(M,256), B:(N,256) row-major; D row-major (M,N)
template <bool AF32, bool BF32, bool FINAL>
__global__ __launch_bounds__(256, 2) void gemm_nt(
    const void* __restrict__ Ap, const void* __restrict__ Bp, void* __restrict__ Dp,
    const float* __restrict__ bias, const float* __restrict__ resid,
    int M, int N, long aBS, long bBS, long dBS, long rBS) {
  __shared__ u16 Als[128 * 72];              // 128 rows x 64 k-chunk, +4 u16 pad (16B-aligned rows)
  __shared__ u16 Bls[128 * 72];
  const int tid = threadIdx.x;
  const int lane = tid & 63;
  const int m = lane & 15, quad = lane >> 4;
  const int wid = tid >> 6;
  const int wm = wid & 1, wn = wid >> 1;
  const int m0 = blockIdx.x * 128, n0 = blockIdx.y * 128;
  const int bz = blockIdx.z;

  f32x4 acc[4][4] = {};

  for (int ks = 0; ks < 4; ++ks) {
    const int kb = ks * 64;
    if (ks) __syncthreads();
    if constexpr (AF32) {
      const float* src = (const float*)Ap + aBS * bz;
      #pragma unroll
      for (int it = 0; it < 8; ++it) {
        int idx = it * 1024 + tid * 4;
        int r = idx >> 6, c = idx & 63;
        fltx4 v = *(const fltx4*)(src + (long)(m0 + r) * CDIM + kb + c);
        u32* d = (u32*)&Als[r * 72 + c];
        d[0] = (u32)f2bf(v[0]) | ((u32)f2bf(v[1]) << 16);
        d[1] = (u32)f2bf(v[2]) | ((u32)f2bf(v[3]) << 16);
      }
    } else {
      const u16* src = (const u16*)Ap + aBS * bz;
      #pragma unroll
      for (int it = 0; it < 4; ++it) {
        int idx = it * 2048 + tid * 8;
        int r = idx >> 6, c = idx & 63;
        *(u32x4*)&Als[r * 72 + c] = *(const u32x4*)(src + (long)(m0 + r) * CDIM + kb + c);
      }
    }
    if constexpr (BF32) {
      const float* src = (const float*)Bp + bBS * bz;
      #pragma unroll
      for (int it = 0; it < 8; ++it) {
        int idx = it * 1024 + tid * 4;
        int r = idx >> 6, c = idx & 63;
        fltx4 v = *(const fltx4*)(src + (long)(n0 + r) * CDIM + kb + c);
        u32* d = (u32*)&Bls[r * 72 + c];
        d[0] = (u32)f2bf(v[0]) | ((u32)f2bf(v[1]) << 16);
        d[1] = (u32)f2bf(v[2]) | ((u32)f2bf(v[3]) << 16);
      }
    } else {
      const u16* src = (const u16*)Bp + bBS * bz;
      #pragma unroll
      for (int it = 0; it < 4; ++it) {
        int idx = it * 2048 + tid * 8;
        int r = idx >> 6, c = idx & 63;
        *(u32x4*)&Bls[r * 72 + c] = *(const u32x4*)(src + (long)(n0 + r) * CDIM + kb + c);
      }
    }
    __syncthreads();
    #pragma unroll
    for (int s = 0; s < 2; ++s) {
      bf16x8 av[4], bv[4];
      #pragma unroll
      for (int i = 0; i < 4; ++i)
        av[i] = *(const bf16x8*)&Als[(wm * 64 + i * 16 + m) * 72 + s * 32 + quad * 8];
      #pragma unroll
      for (int i = 0; i < 4; ++i)
        bv[i] = *(const bf16x8*)&Bls[(wn * 64 + i * 16 + m) * 72 + s * 32 + quad * 8];
      #pragma unroll
      for (int mi = 0; mi < 4; ++mi)
        #pragma unroll
        for (int ni = 0; ni < 4; ++ni)
          acc[mi][ni] = __builtin_amdgcn_mfma_f32_16x16x32_bf16(av[mi], bv[ni], acc[mi][ni], 0, 0, 0);
    }
  }

  const int row0 = m0 + wm * 64;
  const int col0 = n0 + wn * 64 + m;
  if constexpr (FINAL) {
    float* out = (float*)Dp + dBS * bz;
    const float* res = resid + rBS * bz;
    #pragma unroll
    for (int mi = 0; mi < 4; ++mi)
      #pragma unroll
      for (int r = 0; r < 4; ++r) {
        int row = row0 + mi * 16 + quad * 4 + r;
        float bs = bias[row];
        #pragma unroll
        for (int ni = 0; ni < 4; ++ni) {
          long off = (long)row * N + col0 + ni * 16;
          out[off] = acc[mi][ni][r] + bs + res[off];
        }
      }
  } else {
    u16* out = (u16*)Dp + dBS * bz;
    #pragma unroll
    for (int mi = 0; mi < 4; ++mi)
      #pragma unroll
      for (int r = 0; r < 4; ++r) {
        int row = row0 + mi * 16 + quad * 4 + r;
        #pragma unroll
        for (int ni = 0; ni < 4; ++ni)
          out[(long)row * N + col0 + ni * 16] = f2bf(acc[mi][ni][r]);
      }
  }
}

// ------------------------------------------------------------------- flash attention
// Kt: (B, 4096, 256) bf16 ; V: (B, 256, 4096) bf16 ; Ot out: (B, 4096, 256) bf16
__global__ __launch_bounds__(256, 2) void attn_kernel(
    const float* __restrict__ quary, const float* __restrict__ wq,
    const u16* __restrict__ Kt, const u16* __restrict__ V, u16* __restrict__ Ot) {
  __shared__ u16 KtLS[64 * 256];   // 32 KB, key-rows x 256 ch, XOR-swizzled 16B chunks
  __shared__ u16 VLS[256 * 64];    // 32 KB, ch-rows x 64 keys, XOR-swizzled
  const int tid = threadIdx.x, lane = tid & 63, w = tid >> 6;
  const int m = lane & 15, quad = lane >> 4;
  const int b = blockIdx.y;
  const int qbase = blockIdx.x * 64;
  const int qrow = qbase + w * 16 + m;

  // ---- Q fragments in-register: q[c] = sum_i wq[c][i]*quary[b][i][qrow], scaled
  U8 aq[8];
  {
    const float qy0 = quary[b * 12288 + qrow];
    const float qy1 = quary[b * 12288 + 4096 + qrow];
    const float qy2 = quary[b * 12288 + 8192 + qrow];
    #pragma unroll
    for (int s = 0; s < 8; ++s)
      #pragma unroll
      for (int j = 0; j < 8; ++j) {
        int c = s * 32 + quad * 8 + j;
        float v = (wq[c * 3] * qy0 + wq[c * 3 + 1] * qy1 + wq[c * 3 + 2] * qy2) * QSCALE;
        aq[s].u[j] = f2bf(v);
      }
  }

  float mOld[4], lSum[4];
  #pragma unroll
  for (int r = 0; r < 4; ++r) { mOld[r] = -__builtin_inff(); lSum[r] = 0.f; }
  f32x4 oAcc[16] = {};

  const u16* KtB = Kt + (long)b * NPIX * CDIM;
  const u16* VB  = V  + (long)b * CDIM * NPIX;

  for (int kt = 0; kt < 64; ++kt) {
    const int j0 = kt * 64;
    // stage K tile: rows j (64) x 256ch, chunk swizzle ch^(j&31)
    #pragma unroll
    for (int it = 0; it < 8; ++it) {
      int gidx = it * 256 + tid;
      int j = gidx >> 5, ch = gidx & 31;
      u32x4 vv = *(const u32x4*)(KtB + (long)(j0 + j) * CDIM + ch * 8);
      *(u32x4*)&KtLS[j * 256 + ((ch ^ (j & 31)) << 3)] = vv;
    }
    // stage V tile: rows c (256) x 64 keys, chunk swizzle ch^(c&7)
    #pragma unroll
    for (int it = 0; it < 8; ++it) {
      int gidx = it * 256 + tid;
      int c = gidx >> 3, ch = gidx & 7;
      u32x4 vv = *(const u32x4*)(VB + (long)c * NPIX + j0 + ch * 8);
      *(u32x4*)&VLS[c * 64 + ((ch ^ (c & 7)) << 3)] = vv;
    }
    __syncthreads();

    // ---- S = Q^T K  (16 q-rows x 64 keys per wave)
    f32x4 sv[4] = {};
    #pragma unroll
    for (int s = 0; s < 8; ++s)
      #pragma unroll
      for (int t = 0; t < 4; ++t) {
        int j = t * 16 + m;
        bf16x8 bk = *(const bf16x8*)&KtLS[j * 256 + (((s * 4 + quad) ^ (j & 31)) << 3)];
        sv[t] = __builtin_amdgcn_mfma_f32_16x16x32_bf16(aq[s].v, bk, sv[t], 0, 0, 0);
      }

    // ---- online softmax (exp2 domain; scale folded into Q)
    float alpha[4];
    u16 pbf[4][4];
    #pragma unroll
    for (int r = 0; r < 4; ++r) {
      float rm = fmaxf(fmaxf(sv[0][r], sv[1][r]), fmaxf(sv[2][r], sv[3][r]));
      rm = fmaxf(rm, __shfl_xor(rm, 1));
      rm = fmaxf(rm, __shfl_xor(rm, 2));
      rm = fmaxf(rm, __shfl_xor(rm, 4));
      rm = fmaxf(rm, __shfl_xor(rm, 8));
      float mNew = fmaxf(mOld[r], rm);
      alpha[r] = exp2f(mOld[r] - mNew);
      float ps = 0.f;
      #pragma unroll
      for (int t = 0; t < 4; ++t) {
        float p = exp2f(sv[t][r] - mNew);
        ps += p;
        pbf[t][r] = f2bf(p);
      }
      lSum[r] = lSum[r] * alpha[r] + ps;
      mOld[r] = mNew;
    }
    __syncthreads();   // all S-phase reads of KtLS done before P overwrites it

    // ---- P (C-layout) -> LDS -> A-layout; per-wave private 8KB region of KtLS
    u16* P = &KtLS[w * 4096];
    #pragma unroll
    for (int t = 0; t < 4; ++t) {
      int jl = t * 16 + m;
      int ch = jl >> 3, jlo = jl & 7;
      #pragma unroll
      for (int r = 0; r < 4; ++r) {
        int mr = quad * 4 + r;
        P[mr * 64 + ((ch ^ (mr & 7)) << 3) + jlo] = pbf[t][r];
      }
    }
    // rescale O by alpha
    #pragma unroll
    for (int ct = 0; ct < 16; ++ct)
      #pragma unroll
      for (int r = 0; r < 4; ++r) oAcc[ct][r] *= alpha[r];
    // ---- O += P * V^T
    #pragma unroll
    for (int s = 0; s < 2; ++s) {
      bf16x8 pa = *(const bf16x8*)&P[m * 64 + (((s * 4 + quad) ^ (m & 7)) << 3)];
      #pragma unroll
      for (int ct = 0; ct < 16; ++ct) {
        int c = ct * 16 + m;
        bf16x8 bv = *(const bf16x8*)&VLS[c * 64 + (((s * 4 + quad) ^ (c & 7)) << 3)];
        oAcc[ct] = __builtin_amdgcn_mfma_f32_16x16x32_bf16(pa, bv, oAcc[ct], 0, 0, 0);
      }
    }
    __syncthreads();   // protect KtLS/VLS before next stage
  }

  // ---- finalize: l = cross-lane sum, O /= l, store Ot[b][n][c] bf16
  float inv[4];
  #pragma unroll
  for (int r = 0; r < 4; ++r) {
    float ls = lSum[r];
    ls += __shfl_xor(ls, 1);
    ls += __shfl_xor(ls, 2);
    ls += __shfl_xor(ls, 4);
    ls += __shfl_xor(ls, 8);
    inv[r] = 1.f / ls;
  }
  u16* OtB = Ot + ((long)b * NPIX + qbase + w * 16) * CDIM;
  #pragma unroll
  for (int ct = 0; ct < 16; ++ct)
    #pragma unroll
    for (int r = 0; r < 4; ++r) {
      int row = quad * 4 + r;
      OtB[row * CDIM + ct * 16 + m] = f2bf(oAcc[ct][r] * inv[r]);
    }
}

// ----------------------------------------------------------------------- launch
extern "C" void kernel_launch(void* const* d_in, const int* in_sizes, int n_in,
                              void* d_out, int out_size, void* d_ws, size_t ws_size,
                              hipStream_t stream) {
  (void)in_sizes; (void)n_in; (void)out_size; (void)ws_size;
  const float* input = (const float*)d_in[0];   // (8,256,64,64)
  const float* quary = (const float*)d_in[1];   // (8,3,64,64)
  const float* gnw   = (const float*)d_in[2];   // (256)
  const float* gnb   = (const float*)d_in[3];   // (256)
  const float* wq    = (const float*)d_in[4];   // (256,3)
  const float* wkv   = (const float*)d_in[5];   // (512,256)
  const float* wout  = (const float*)d_in[6];   // (256,256)
  const float* bout  = (const float*)d_in[7];   // (256)
  float* out = (float*)d_out;

  char* ws = (char*)d_ws;
  float* stats = (float*)ws;                              // 2KB
  u16* normT = (u16*)(ws + 4096);                         // 16MB (B,N,C)
  u16* Kt    = (u16*)(ws + 4096 + 1L * 16777216);         // 16MB (B,N,C)
  u16* Vv    = (u16*)(ws + 4096 + 2L * 16777216);         // 16MB (B,C,N)
  u16* Ot    = (u16*)(ws + 4096 + 3L * 16777216);         // 16MB (B,N,C)

  const long S = (long)NPIX * CDIM;                       // 1048576 per-batch stride

  gn_stats<<<256, 256, 0, stream>>>(input, stats);
  gn_apply<<<dim3(64, 4, 8), 256, 0, stream>>>(input, stats, gnw, gnb, normT);
  // Kt[n][o] = sum_c normT[n][c] * wkv[o][c]   (o = 0..255, key part)
  gemm_nt<false, true, false><<<dim3(32, 2, 8), 256, 0, stream>>>(
      normT, wkv, Kt, nullptr, nullptr, 4096, 256, S, 0, S, 0);
  // V[o][n] = sum_c wkv[256+o][c] * normT[n][c]
  gemm_nt<true, false, false><<<dim3(2, 32, 8), 256, 0, stream>>>(
      wkv + 256 * 256, normT, Vv, nullptr, nullptr, 256, 4096, 0, S, S, 0);
  attn_kernel<<<dim3(64, 8), 256, 0, stream>>>(quary, wq, Kt, Vv, Ot);
  // out[o][n] = sum_c wout[o][c]*Ot[n][c] + bout[o] + input[o][n]
  gemm_nt<true, false, true><<<dim3(2, 32, 8), 256, 0, stream>>>(
      wout, Ot, out, bout, input, 256, 4096, 0, S, S, S);
}

// Round 2
// 572.112 us; speedup vs baseline: 1.1445x; 1.1445x over previous
//
#include <hip/hip_runtime.h>

typedef unsigned short u16;
typedef unsigned int   u32;
typedef float  f32x4  __attribute__((ext_vector_type(4)));
typedef float  fltx4  __attribute__((ext_vector_type(4)));
typedef short  bf16x8 __attribute__((ext_vector_type(8)));  // 8 bf16 bits in 4 VGPRs
typedef u32    u32x4  __attribute__((ext_vector_type(4)));

#define CDIM 256
#define NPIX 4096
// (1/sqrt(256)) * log2(e): fold attention scale + exp2 conversion into Q
#define QSCALE 0.09016843736f

__device__ __forceinline__ u16 f2bf(float f) {
  u32 u = __builtin_bit_cast(u32, f);
  u += 0x7fffu + ((u >> 16) & 1u);          // RNE truncate to bf16
  return (u16)(u >> 16);
}

union U8 { bf16x8 v; u16 u[8]; };

// async 16B/lane global->LDS DMA; lds_base is wave-uniform, HW adds lane*16
__device__ __forceinline__ void llds16(u16* lds_base, const u16* gsrc) {
  __builtin_amdgcn_global_load_lds(
      (const __attribute__((address_space(1))) unsigned int*)gsrc,
      (__attribute__((address_space(3))) unsigned int*)lds_base, 16, 0, 0);
}

// ---------------------------------------------------------------- groupnorm stats
__global__ __launch_bounds__(256) void gn_stats(const float* __restrict__ x,
                                                float* __restrict__ stats) {
  int bg = blockIdx.x;                       // b*32 + g ; group = 8 ch x 4096 contiguous
  const float* base = x + (long)bg * 32768;
  float s = 0.f, s2 = 0.f;
  for (int i = threadIdx.x; i < 8192; i += 256) {
    fltx4 v = ((const fltx4*)base)[i];
    s  += v[0] + v[1] + v[2] + v[3];
    s2 += v[0]*v[0] + v[1]*v[1] + v[2]*v[2] + v[3]*v[3];
  }
  for (int off = 1; off < 64; off <<= 1) {
    s  += __shfl_xor(s, off);
    s2 += __shfl_xor(s2, off);
  }
  __shared__ float red[8];
  int w = threadIdx.x >> 6;
  if ((threadIdx.x & 63) == 0) { red[w] = s; red[4 + w] = s2; }
  __syncthreads();
  if (threadIdx.x == 0) {
    float S  = red[0] + red[1] + red[2] + red[3];
    float S2 = red[4] + red[5] + red[6] + red[7];
    float mean = S * (1.f / 32768.f);
    float var  = S2 * (1.f / 32768.f) - mean * mean;
    stats[bg * 2]     = mean;
    stats[bg * 2 + 1] = rsqrtf(var + 1e-5f);
  }
}

// ------------------------------------------- normalize + transpose -> normT[b][n][c] bf16
__global__ __launch_bounds__(256) void gn_apply(const float* __restrict__ x,
                                                const float* __restrict__ stats,
                                                const float* __restrict__ gamma,
                                                const float* __restrict__ beta,
                                                u16* __restrict__ normT) {
  __shared__ u16 tile[64 * 66];
  const int b = blockIdx.z, cb = blockIdx.y * 64, nb = blockIdx.x * 64;
  const int nIn = threadIdx.x & 63, c4 = threadIdx.x >> 6;
  const float* xb = x + (long)b * (CDIM * NPIX);
  #pragma unroll 4
  for (int p = 0; p < 16; ++p) {
    int cl = c4 * 16 + p;
    int c = cb + cl;
    int g = c >> 3;
    float mean = stats[(b * 32 + g) * 2];
    float rstd = stats[(b * 32 + g) * 2 + 1];
    float v = xb[(long)c * NPIX + nb + nIn];
    tile[cl * 66 + nIn] = f2bf((v - mean) * rstd * gamma[c] + beta[c]);
  }
  __syncthreads();
  u16* nT = normT + ((long)b * NPIX + nb) * CDIM + cb;
  const int cOut = threadIdx.x & 63, n4 = threadIdx.x >> 6;
  #pragma unroll 4
  for (int p = 0; p < 16; ++p) {
    int nl = n4 * 16 + p;
    nT[(long)nl * CDIM + cOut] = tile[cOut * 66 + nl];
  }
}

// ------------------------------------------------------------ generic NT GEMM, K=256
// D[m][n] = sum_k A[m][k]*B[n][k]; A:(M,256), B:(N,256) row-major; D row-major (M,N)
template <bool AF32, bool BF32, bool FINAL>
__global__ __launch_bounds__(256, 2) void gemm_nt(
    const void* __restrict__ Ap, const void* __restrict__ Bp, void* __restrict__ Dp,
    const float* __restrict__ bias, const float* __restrict__ resid,
    int M, int N, long aBS, long bBS, long dBS, long rBS) {
  __shared__ u16 Als[128 * 72];              // 128 rows x 64 k-chunk, +4 u16 pad
  __shared__ u16 Bls[128 * 72];
  const int tid = threadIdx.x;
  const int lane = tid & 63;
  const int m = lane & 15, quad = lane >> 4;
  const int wid = tid >> 6;
  const int wm = wid & 1, wn = wid >> 1;
  const int m0 = blockIdx.x * 128, n0 = blockIdx.y * 128;
  const int bz = blockIdx.z;

  f32x4 acc[4][4] = {};

  for (int ks = 0; ks < 4; ++ks) {
    const int kb = ks * 64;
    if (ks) __syncthreads();
    if constexpr (AF32) {
      const float* src = (const float*)Ap + aBS * bz;
      #pragma unroll
      for (int it = 0; it < 8; ++it) {
        int idx = it * 1024 + tid * 4;
        int r = idx >> 6, c = idx & 63;
        fltx4 v = *(const fltx4*)(src + (long)(m0 + r) * CDIM + kb + c);
        u32* d = (u32*)&Als[r * 72 + c];
        d[0] = (u32)f2bf(v[0]) | ((u32)f2bf(v[1]) << 16);
        d[1] = (u32)f2bf(v[2]) | ((u32)f2bf(v[3]) << 16);
      }
    } else {
      const u16* src = (const u16*)Ap + aBS * bz;
      #pragma unroll
      for (int it = 0; it < 4; ++it) {
        int idx = it * 2048 + tid * 8;
        int r = idx >> 6, c = idx & 63;
        *(u32x4*)&Als[r * 72 + c] = *(const u32x4*)(src + (long)(m0 + r) * CDIM + kb + c);
      }
    }
    if constexpr (BF32) {
      const float* src = (const float*)Bp + bBS * bz;
      #pragma unroll
      for (int it = 0; it < 8; ++it) {
        int idx = it * 1024 + tid * 4;
        int r = idx >> 6, c = idx & 63;
        fltx4 v = *(const fltx4*)(src + (long)(n0 + r) * CDIM + kb + c);
        u32* d = (u32*)&Bls[r * 72 + c];
        d[0] = (u32)f2bf(v[0]) | ((u32)f2bf(v[1]) << 16);
        d[1] = (u32)f2bf(v[2]) | ((u32)f2bf(v[3]) << 16);
      }
    } else {
      const u16* src = (const u16*)Bp + bBS * bz;
      #pragma unroll
      for (int it = 0; it < 4; ++it) {
        int idx = it * 2048 + tid * 8;
        int r = idx >> 6, c = idx & 63;
        *(u32x4*)&Bls[r * 72 + c] = *(const u32x4*)(src + (long)(n0 + r) * CDIM + kb + c);
      }
    }
    __syncthreads();
    #pragma unroll
    for (int s = 0; s < 2; ++s) {
      bf16x8 av[4], bv[4];
      #pragma unroll
      for (int i = 0; i < 4; ++i)
        av[i] = *(const bf16x8*)&Als[(wm * 64 + i * 16 + m) * 72 + s * 32 + quad * 8];
      #pragma unroll
      for (int i = 0; i < 4; ++i)
        bv[i] = *(const bf16x8*)&Bls[(wn * 64 + i * 16 + m) * 72 + s * 32 + quad * 8];
      #pragma unroll
      for (int mi = 0; mi < 4; ++mi)
        #pragma unroll
        for (int ni = 0; ni < 4; ++ni)
          acc[mi][ni] = __builtin_amdgcn_mfma_f32_16x16x32_bf16(av[mi], bv[ni], acc[mi][ni], 0, 0, 0);
    }
  }

  const int row0 = m0 + wm * 64;
  const int col0 = n0 + wn * 64 + m;
  if constexpr (FINAL) {
    float* out = (float*)Dp + dBS * bz;
    const float* res = resid + rBS * bz;
    #pragma unroll
    for (int mi = 0; mi < 4; ++mi)
      #pragma unroll
      for (int r = 0; r < 4; ++r) {
        int row = row0 + mi * 16 + quad * 4 + r;
        float bs = bias[row];
        #pragma unroll
        for (int ni = 0; ni < 4; ++ni) {
          long off = (long)row * N + col0 + ni * 16;
          out[off] = acc[mi][ni][r] + bs + res[off];
        }
      }
  } else {
    u16* out = (u16*)Dp + dBS * bz;
    #pragma unroll
    for (int mi = 0; mi < 4; ++mi)
      #pragma unroll
      for (int r = 0; r < 4; ++r) {
        int row = row0 + mi * 16 + quad * 4 + r;
        #pragma unroll
        for (int ni = 0; ni < 4; ++ni)
          out[(long)row * N + col0 + ni * 16] = f2bf(acc[mi][ni][r]);
      }
  }
}

// ------------------------------------------------------------------- flash attention
// Kt: (B, 4096, 256) bf16 ; V: (B, 256, 4096) bf16 ; Ot out: (B, 4096, 256) bf16
// 256 threads = 4 waves x 32 q-rows = 128 q-rows/block; grid (32, 8) = 256 blocks.
// Double-buffered K/V tiles staged via global_load_lds (swizzle folded into the
// per-lane GLOBAL address, LDS side stays linear); one barrier per iteration;
// P round-trips through a per-wave private LDS region (lgkmcnt-only).
__global__ __launch_bounds__(256, 1) void attn_kernel(
    const float* __restrict__ quary, const float* __restrict__ wq,
    const u16* __restrict__ Kt, const u16* __restrict__ V, u16* __restrict__ Ot) {
  __shared__ u16 KLS[2][64 * 256];   // 2 x 32 KB, key-rows x 256 ch, chunk ^= (j&31)
  __shared__ u16 VLS[2][256 * 64];   // 2 x 32 KB, ch-rows x 64 keys, chunk ^= (c&7)
  __shared__ u16 PLS[4][32 * 64];    // 4 KB per wave, q-rows x 64 keys, chunk ^= (row&7)
  const int tid = threadIdx.x, lane = tid & 63, w = tid >> 6;
  const int m = lane & 15, quad = lane >> 4;
  const int b = blockIdx.y;
  const int qbase = blockIdx.x * 128;

  // ---- Q fragments in-register: q[c] = sum_i wq[c][i]*quary[b][i][qrow], scaled
  U8 aq[2][8];
  #pragma unroll
  for (int qm = 0; qm < 2; ++qm) {
    const int qrow = qbase + w * 32 + qm * 16 + m;
    const float qy0 = quary[b * 12288 + qrow];
    const float qy1 = quary[b * 12288 + 4096 + qrow];
    const float qy2 = quary[b * 12288 + 8192 + qrow];
    #pragma unroll
    for (int s = 0; s < 8; ++s)
      #pragma unroll
      for (int j = 0; j < 8; ++j) {
        int c = s * 32 + quad * 8 + j;
        float v = (wq[c * 3] * qy0 + wq[c * 3 + 1] * qy1 + wq[c * 3 + 2] * qy2) * QSCALE;
        aq[qm][s].u[j] = f2bf(v);
      }
  }

  float mOld[2][4], lSum[2][4];
  #pragma unroll
  for (int qm = 0; qm < 2; ++qm)
    #pragma unroll
    for (int r = 0; r < 4; ++r) { mOld[qm][r] = -__builtin_inff(); lSum[qm][r] = 0.f; }
  f32x4 oAcc[2][16] = {};

  const u16* KtB = Kt + (long)b * NPIX * CDIM;
  const u16* VB  = V  + (long)b * CDIM * NPIX;

  // staging lambda: wave w stages chunks [w*8, w*8+8) of K and of V (1KB each)
  auto stage_kv = [&](int j0, u16* Kb, u16* Vb) {
    #pragma unroll
    for (int i = 0; i < 8; ++i) {
      int chunk = w * 8 + i;
      int j = chunk * 2 + (lane >> 5);             // key row within tile
      int chs = (lane & 31) ^ (j & 31);            // swizzled source chunk
      llds16(Kb + chunk * 512, KtB + (long)(j0 + j) * CDIM + chs * 8);
    }
    #pragma unroll
    for (int i = 0; i < 8; ++i) {
      int chunk = w * 8 + i;
      int c = chunk * 8 + (lane >> 3);             // channel row
      int chs = (lane & 7) ^ (c & 7);
      llds16(Vb + chunk * 512, VB + (long)c * NPIX + j0 + chs * 8);
    }
  };

  stage_kv(0, KLS[0], VLS[0]);

  for (int kt = 0; kt < 64; ++kt) {
    __syncthreads();   // drains own vmcnt: tile kt staged & all waves done with tile kt-1
    if (kt < 63) stage_kv((kt + 1) * 64, KLS[(kt + 1) & 1], VLS[(kt + 1) & 1]);
    const u16* Kb = KLS[kt & 1];
    const u16* Vb = VLS[kt & 1];

    // ---- S = Q^T K  (32 q-rows x 64 keys per wave; bk shared across both q-tiles)
    f32x4 sv[2][4] = {};
    #pragma unroll
    for (int s = 0; s < 8; ++s)
      #pragma unroll
      for (int t = 0; t < 4; ++t) {
        int j = t * 16 + m;
        bf16x8 bk = *(const bf16x8*)&Kb[j * 256 + (((s * 4 + quad) ^ (j & 31)) << 3)];
        sv[0][t] = __builtin_amdgcn_mfma_f32_16x16x32_bf16(aq[0][s].v, bk, sv[0][t], 0, 0, 0);
        sv[1][t] = __builtin_amdgcn_mfma_f32_16x16x32_bf16(aq[1][s].v, bk, sv[1][t], 0, 0, 0);
      }

    // ---- online softmax (exp2 domain; scale folded into Q)
    float alpha[2][4];
    u16 pbf[2][4][4];
    #pragma unroll
    for (int qm = 0; qm < 2; ++qm)
      #pragma unroll
      for (int r = 0; r < 4; ++r) {
        float rm = fmaxf(fmaxf(sv[qm][0][r], sv[qm][1][r]), fmaxf(sv[qm][2][r], sv[qm][3][r]));
        rm = fmaxf(rm, __shfl_xor(rm, 1));
        rm = fmaxf(rm, __shfl_xor(rm, 2));
        rm = fmaxf(rm, __shfl_xor(rm, 4));
        rm = fmaxf(rm, __shfl_xor(rm, 8));
        float mNew = fmaxf(mOld[qm][r], rm);
        alpha[qm][r] = exp2f(mOld[qm][r] - mNew);
        float ps = 0.f;
        #pragma unroll
        for (int t = 0; t < 4; ++t) {
          float p = exp2f(sv[qm][t][r] - mNew);
          ps += p;
          pbf[qm][t][r] = f2bf(p);
        }
        lSum[qm][r] = lSum[qm][r] * alpha[qm][r] + ps;
        mOld[qm][r] = mNew;
      }

    // ---- P (C-layout) -> private LDS -> A-layout (same-wave, no barrier)
    u16* P = PLS[w];
    #pragma unroll
    for (int qm = 0; qm < 2; ++qm)
      #pragma unroll
      for (int t = 0; t < 4; ++t) {
        int jl = t * 16 + m, ch = jl >> 3, jlo = jl & 7;
        #pragma unroll
        for (int r = 0; r < 4; ++r) {
          int row = qm * 16 + quad * 4 + r;
          P[row * 64 + ((ch ^ (row & 7)) << 3) + jlo] = pbf[qm][t][r];
        }
      }
    // rescale O by alpha while P writes land
    #pragma unroll
    for (int qm = 0; qm < 2; ++qm)
      #pragma unroll
      for (int ct = 0; ct < 16; ++ct)
        #pragma unroll
        for (int r = 0; r < 4; ++r) oAcc[qm][ct][r] *= alpha[qm][r];

    // ---- O += P * V^T  (bv shared across both q-tiles)
    #pragma unroll
    for (int s = 0; s < 2; ++s) {
      bf16x8 pa0 = *(const bf16x8*)&P[(m)      * 64 + (((s * 4 + quad) ^ (m & 7)) << 3)];
      bf16x8 pa1 = *(const bf16x8*)&P[(16 + m) * 64 + (((s * 4 + quad) ^ (m & 7)) << 3)];
      #pragma unroll
      for (int ct = 0; ct < 16; ++ct) {
        int c = ct * 16 + m;
        bf16x8 bv = *(const bf16x8*)&Vb[c * 64 + (((s * 4 + quad) ^ (c & 7)) << 3)];
        oAcc[0][ct] = __builtin_amdgcn_mfma_f32_16x16x32_bf16(pa0, bv, oAcc[0][ct], 0, 0, 0);
        oAcc[1][ct] = __builtin_amdgcn_mfma_f32_16x16x32_bf16(pa1, bv, oAcc[1][ct], 0, 0, 0);
      }
    }
  }

  // ---- finalize: l = cross-lane sum, O /= l, store Ot[b][n][c] bf16
  float inv[2][4];
  #pragma unroll
  for (int qm = 0; qm < 2; ++qm)
    #pragma unroll
    for (int r = 0; r < 4; ++r) {
      float ls = lSum[qm][r];
      ls += __shfl_xor(ls, 1);
      ls += __shfl_xor(ls, 2);
      ls += __shfl_xor(ls, 4);
      ls += __shfl_xor(ls, 8);
      inv[qm][r] = 1.f / ls;
    }
  u16* OtB = Ot + ((long)b * NPIX + qbase + w * 32) * CDIM;
  #pragma unroll
  for (int qm = 0; qm < 2; ++qm)
    #pragma unroll
    for (int ct = 0; ct < 16; ++ct)
      #pragma unroll
      for (int r = 0; r < 4; ++r) {
        int row = qm * 16 + quad * 4 + r;
        OtB[row * CDIM + ct * 16 + m] = f2bf(oAcc[qm][ct][r] * inv[qm][r]);
      }
}

// ----------------------------------------------------------------------- launch
extern "C" void kernel_launch(void* const* d_in, const int* in_sizes, int n_in,
                              void* d_out, int out_size, void* d_ws, size_t ws_size,
                              hipStream_t stream) {
  (void)in_sizes; (void)n_in; (void)out_size; (void)ws_size;
  const float* input = (const float*)d_in[0];   // (8,256,64,64)
  const float* quary = (const float*)d_in[1];   // (8,3,64,64)
  const float* gnw   = (const float*)d_in[2];   // (256)
  const float* gnb   = (const float*)d_in[3];   // (256)
  const float* wq    = (const float*)d_in[4];   // (256,3)
  const float* wkv   = (const float*)d_in[5];   // (512,256)
  const float* wout  = (const float*)d_in[6];   // (256,256)
  const float* bout  = (const float*)d_in[7];   // (256)
  float* out = (float*)d_out;

  char* ws = (char*)d_ws;
  float* stats = (float*)ws;                              // 2KB
  u16* normT = (u16*)(ws + 4096);                         // 16MB (B,N,C)
  u16* Kt    = (u16*)(ws + 4096 + 1L * 16777216);         // 16MB (B,N,C)
  u16* Vv    = (u16*)(ws + 4096 + 2L * 16777216);         // 16MB (B,C,N)
  u16* Ot    = (u16*)(ws + 4096 + 3L * 16777216);         // 16MB (B,N,C)

  const long S = (long)NPIX * CDIM;                       // 1048576 per-batch stride

  gn_stats<<<256, 256, 0, stream>>>(input, stats);
  gn_apply<<<dim3(64, 4, 8), 256, 0, stream>>>(input, stats, gnw, gnb, normT);
  // Kt[n][o] = sum_c normT[n][c] * wkv[o][c]   (o = 0..255, key part)
  gemm_nt<false, true, false><<<dim3(32, 2, 8), 256, 0, stream>>>(
      normT, wkv, Kt, nullptr, nullptr, 4096, 256, S, 0, S, 0);
  // V[o][n] = sum_c wkv[256+o][c] * normT[n][c]
  gemm_nt<true, false, false><<<dim3(2, 32, 8), 256, 0, stream>>>(
      wkv + 256 * 256, normT, Vv, nullptr, nullptr, 256, 4096, 0, S, S, 0);
  attn_kernel<<<dim3(32, 8), 256, 0, stream>>>(quary, wq, Kt, Vv, Ot);
  // out[o][n] = sum_c wout[o][c]*Ot[n][c] + bout[o] + input[o][n]
  gemm_nt<true, false, true><<<dim3(2, 32, 8), 256, 0, stream>>>(
      wout, Ot, out, bout, input, 256, 4096, 0, S, S, S);
}